// Round 3
// baseline (4762.268 us; speedup 1.0000x reference)
//
#include <hip/hip_runtime.h>
#include <math.h>

#define BN 4
#define HW 1024
#define SP 1024

static constexpr float EPS = 1e-5f;
static constexpr float TEMPF = 3.0f;
static constexpr float MASK_FILL = 1e-4f;

// ---------------- reductions ----------------
__device__ __forceinline__ float wave_max(float v) {
    for (int o = 32; o; o >>= 1) v = fmaxf(v, __shfl_xor(v, o));
    return v;
}
__device__ __forceinline__ float wave_sum(float v) {
    for (int o = 32; o; o >>= 1) v += __shfl_xor(v, o);
    return v;
}
__device__ __forceinline__ float block_max(float v, float* red) {
    v = wave_max(v);
    int w = threadIdx.x >> 6;
    if ((threadIdx.x & 63) == 0) red[w] = v;
    __syncthreads();
    v = fmaxf(fmaxf(red[0], red[1]), fmaxf(red[2], red[3]));
    __syncthreads();
    return v;
}
__device__ __forceinline__ float block_sum(float v, float* red) {
    v = wave_sum(v);
    int w = threadIdx.x >> 6;
    if ((threadIdx.x & 63) == 0) red[w] = v;
    __syncthreads();
    v = red[0] + red[1] + red[2] + red[3];
    __syncthreads();
    return v;
}

// ---------------- column max over hw for each sp (per batch) ----------------
__global__ void colmax_part(const float* __restrict__ in, float* __restrict__ part) {
    int ch = blockIdx.x;
    const float* base = in + (size_t)ch * 32 * SP;
    float m[4] = {-INFINITY, -INFINITY, -INFINITY, -INFINITY};
    for (int r = 0; r < 32; ++r) {
        const float* row = base + (size_t)r * SP;
#pragma unroll
        for (int k = 0; k < 4; ++k) m[k] = fmaxf(m[k], row[threadIdx.x + k * 256]);
    }
    float* p = part + (size_t)ch * SP;
#pragma unroll
    for (int k = 0; k < 4; ++k) p[threadIdx.x + k * 256] = m[k];
}

__global__ void colmax_comb(const float* __restrict__ part, float* __restrict__ binv) {
    int col = (blockIdx.x << 8) + threadIdx.x;
    float m = -INFINITY;
    for (int c = 0; c < 32; ++c) m = fmaxf(m, part[(size_t)c * SP + col]);
    binv[col] = 1.0f / (m + EPS);
}

// ---------------- mutual matching (row-max fused), per batch ----------------
__global__ void mm_rows(const float* __restrict__ in, const float* __restrict__ binv,
                        float* __restrict__ out) {
    __shared__ float red[4];
    int row = blockIdx.x;
    const float* r = in + (size_t)row * SP;
    float v[4];
#pragma unroll
    for (int k = 0; k < 4; ++k) v[k] = r[threadIdx.x + k * 256];
    float m = fmaxf(fmaxf(v[0], v[1]), fmaxf(v[2], v[3]));
    m = block_max(m, red);
    float rinv = 1.0f / (m + EPS);
    float* o = out + (size_t)row * SP;
#pragma unroll
    for (int k = 0; k < 4; ++k) {
        int sp = threadIdx.x + k * 256;
        o[sp] = v[k] * v[k] * v[k] * rinv * binv[sp];
    }
}

// ---------------- 4D conv layer (per batch), no LDS tile ----------------
// out[co,h,w,hs,ws] = relu( b1[co]+b2[co]
//    + sum_ci,tap in[ci,h+dh,w+dw,hs,ws]*whw[co,ci,tap]      (o1: neighbor planes)
//    + sum_ci,tap in[ci,h,w,hs+dh,ws+dw]*wsp[co,ci,tap] )    (o2: in-plane shifts)
// grid: HW blocks (one (h,w) each), 256 thr; thread owns 4 CONSECUTIVE sp.
template <int CI, int CO, bool ADD>
__global__ __launch_bounds__(256, 4) void conv4d(const float* __restrict__ in,
                                                 float* __restrict__ out,
                                                 const float* __restrict__ whw,
                                                 const float* __restrict__ bhw,
                                                 const float* __restrict__ wsp,
                                                 const float* __restrict__ bsp) {
    // weights transposed to [ci][tap][co] so per-tap CO weights are contiguous
    __shared__ float w1l[CI * 9 * CO];
    __shared__ float w2l[CI * 9 * CO];
    int hw = blockIdx.x;
    int h = hw >> 5, w = hw & 31;
    int tid = threadIdx.x;
    int p4 = tid << 2;       // first of 4 consecutive sp
    int ws0 = p4 & 31;       // ws of first element (hs identical for all 4)
    int hs = p4 >> 5;

    for (int i = tid; i < CI * 9 * CO; i += 256) {
        int co = i % CO;
        int ct = i / CO;  // ci*9+tap
        int tap = ct % 9, ci = ct / 9;
        w1l[i] = whw[(co * CI + ci) * 9 + tap];
        w2l[i] = wsp[(co * CI + ci) * 9 + tap];
    }
    __syncthreads();

    float acc[CO][4];
#pragma unroll
    for (int co = 0; co < CO; ++co) {
        float bsum = bhw[co] + bsp[co];
#pragma unroll
        for (int k = 0; k < 4; ++k) acc[co][k] = bsum;
    }

    for (int ci = 0; ci < CI; ++ci) {
        const float* inc = in + (size_t)ci * HW * SP;
        const float* plane = inc + (size_t)hw * SP;
#pragma unroll
        for (int dh = -1; dh <= 1; ++dh) {
            bool hok = (unsigned)(h + dh) < 32u;
            bool v2 = (unsigned)(hs + dh) < 32u;
            int b2 = p4 + dh * 32;
            float4 c4 = {0.f, 0.f, 0.f, 0.f};
            if (v2) c4 = *(const float4*)&plane[b2];
            float lm = (v2 && ws0 > 0) ? plane[b2 - 1] : 0.0f;
            float lp = (v2 && ws0 < 28) ? plane[b2 + 4] : 0.0f;
            float4 l4[3];
            l4[0] = {lm, c4.x, c4.y, c4.z};     // dw=-1
            l4[1] = c4;                          // dw=0
            l4[2] = {c4.y, c4.z, c4.w, lp};     // dw=+1
#pragma unroll
            for (int dwi = 0; dwi < 3; ++dwi) {
                int dw = dwi - 1;
                bool v1 = hok && ((unsigned)(w + dw) < 32u);
                float4 g4 = {0.f, 0.f, 0.f, 0.f};
                if (v1) g4 = *(const float4*)&inc[(size_t)(hw + dh * 32 + dw) * SP + p4];
                int tap = (dh + 1) * 3 + dwi;
                const float* w1p = &w1l[(ci * 9 + tap) * CO];
                const float* w2p = &w2l[(ci * 9 + tap) * CO];
#pragma unroll
                for (int co = 0; co < CO; ++co) {
                    float w1v = w1p[co], w2v = w2p[co];
                    acc[co][0] = fmaf(g4.x, w1v, fmaf(l4[dwi].x, w2v, acc[co][0]));
                    acc[co][1] = fmaf(g4.y, w1v, fmaf(l4[dwi].y, w2v, acc[co][1]));
                    acc[co][2] = fmaf(g4.z, w1v, fmaf(l4[dwi].z, w2v, acc[co][2]));
                    acc[co][3] = fmaf(g4.w, w1v, fmaf(l4[dwi].w, w2v, acc[co][3]));
                }
            }
        }
    }

#pragma unroll
    for (int co = 0; co < CO; ++co) {
        float* op = out + ((size_t)co * HW + hw) * SP + p4;
        float4 r;
        r.x = fmaxf(acc[co][0], 0.0f);
        r.y = fmaxf(acc[co][1], 0.0f);
        r.z = fmaxf(acc[co][2], 0.0f);
        r.w = fmaxf(acc[co][3], 0.0f);
        if (ADD) {
            float4 old = *(const float4*)op;
            r.x += old.x; r.y += old.y; r.z += old.z; r.w += old.w;
        }
        *(float4*)op = r;
    }
}

// ---------------- mutual matching + mask + softmax (per batch) ----------------
__global__ void mm_softmax(const float* __restrict__ s, const float* __restrict__ binv,
                           const int* __restrict__ mask, float* __restrict__ attn) {
    __shared__ float red[4];
    int row = blockIdx.x;
    const float* r = s + (size_t)row * SP;
    float v[4];
#pragma unroll
    for (int k = 0; k < 4; ++k) v[k] = r[threadIdx.x + k * 256];
    float m = fmaxf(fmaxf(v[0], v[1]), fmaxf(v[2], v[3]));
    m = block_max(m, red);
    float rinv = 1.0f / (m + EPS);
    float lg[4];
#pragma unroll
    for (int k = 0; k < 4; ++k) {
        int sp = threadIdx.x + k * 256;
        float val = v[k] * v[k] * v[k] * rinv * binv[sp];
        if (mask[sp] != 0) val = MASK_FILL;
        lg[k] = val * TEMPF;
    }
    float lm = fmaxf(fmaxf(lg[0], lg[1]), fmaxf(lg[2], lg[3]));
    lm = block_max(lm, red);
    float e[4], ss = 0.0f;
#pragma unroll
    for (int k = 0; k < 4; ++k) {
        e[k] = expf(lg[k] - lm);
        ss += e[k];
    }
    ss = block_sum(ss, red);
    float inv = 1.0f / ss;
    float* o = attn + (size_t)row * SP;
#pragma unroll
    for (int k = 0; k < 4; ++k) o[threadIdx.x + k * 256] = e[k] * inv;
}

// ---------------- einsum GEMM: out[c,q] = sum_s V[c,s]*A[q,s] (per batch) ----------------
__global__ __launch_bounds__(256) void gemm_vat(const float* __restrict__ V,
                                                const float* __restrict__ A,
                                                float* __restrict__ out) {
    __shared__ float As[64][36];
    __shared__ float Bs[64][36];
    int c0 = blockIdx.y * 64, q0 = blockIdx.x * 64;
    int tr = threadIdx.x & 15, tc = threadIdx.x >> 4;
    float acc[4][4] = {};
    for (int k0 = 0; k0 < 1024; k0 += 32) {
#pragma unroll
        for (int j = 0; j < 2; ++j) {
            int idx = threadIdx.x + j * 256;
            int row = idx >> 3, c4 = (idx & 7) * 4;
            *(float4*)&As[row][c4] = *(const float4*)&V[(size_t)(c0 + row) * 1024 + k0 + c4];
            *(float4*)&Bs[row][c4] = *(const float4*)&A[(size_t)(q0 + row) * 1024 + k0 + c4];
        }
        __syncthreads();
#pragma unroll
        for (int kk = 0; kk < 8; ++kk) {
            float4 a[4], bb[4];
#pragma unroll
            for (int i = 0; i < 4; ++i) a[i] = *(float4*)&As[tr * 4 + i][kk * 4];
#pragma unroll
            for (int j = 0; j < 4; ++j) bb[j] = *(float4*)&Bs[tc * 4 + j][kk * 4];
#pragma unroll
            for (int i = 0; i < 4; ++i)
#pragma unroll
                for (int j = 0; j < 4; ++j)
                    acc[i][j] += a[i].x * bb[j].x + a[i].y * bb[j].y +
                                 a[i].z * bb[j].z + a[i].w * bb[j].w;
        }
        __syncthreads();
    }
#pragma unroll
    for (int i = 0; i < 4; ++i) {
        float4 o = {acc[i][0], acc[i][1], acc[i][2], acc[i][3]};
        *(float4*)&out[(size_t)(c0 + tr * 4 + i) * 1024 + q0 + tc * 4] = o;
    }
}

extern "C" void kernel_launch(void* const* d_in, const int* in_sizes, int n_in,
                              void* d_out, int out_size, void* d_ws, size_t ws_size,
                              hipStream_t stream) {
    const float* corr = (const float*)d_in[0];
    const float* v = (const float*)d_in[1];
    const int* mask = (const int*)d_in[2];
    const float* l0w1 = (const float*)d_in[3];
    const float* l0b1 = (const float*)d_in[4];
    const float* l0w2 = (const float*)d_in[5];
    const float* l0b2 = (const float*)d_in[6];
    const float* l1w1 = (const float*)d_in[7];
    const float* l1b1 = (const float*)d_in[8];
    const float* l1w2 = (const float*)d_in[9];
    const float* l1b2 = (const float*)d_in[10];
    const float* l2w1 = (const float*)d_in[11];
    const float* l2b1 = (const float*)d_in[12];
    const float* l2w2 = (const float*)d_in[13];
    const float* l2b2 = (const float*)d_in[14];

    // per-batch workspace: P,Q (10ch) + C1,S (1ch) + reductions  ~92.4 MB
    float* W = (float*)d_ws;
    const size_t CH10 = (size_t)10 * HW * SP;
    const size_t CH1 = (size_t)HW * SP;
    float* P = W;
    float* Q = P + CH10;
    float* C1 = Q + CH10;
    float* S = C1 + CH1;
    float* PART = S + CH1;
    float* MB0 = PART + 32 * SP;
    float* MB1 = MB0 + SP;
    float* ATTN = C1;  // C1 dead after branch-2 layer 0 of this batch
    float* out = (float*)d_out;
    (void)in_sizes; (void)n_in; (void)out_size; (void)ws_size;

    for (int b = 0; b < BN; ++b) {
        const float* corr_b = corr + (size_t)b * HW * SP;
        const float* v_b = v + (size_t)b * 256 * SP;
        const int* mask_b = mask + (size_t)b * SP;
        float* out_b = out + (size_t)b * 256 * SP;

        // first mutual matching
        colmax_part<<<32, 256, 0, stream>>>(corr_b, PART);
        colmax_comb<<<4, 256, 0, stream>>>(PART, MB0);
        mm_rows<<<HW, 256, 0, stream>>>(corr_b, MB0, C1);

        // branch 1: (h,w)-conv uses w1, (hs,ws)-conv uses w2
        conv4d<1, 10, false><<<HW, 256, 0, stream>>>(C1, P, l0w1, l0b1, l0w2, l0b2);
        conv4d<10, 10, false><<<HW, 256, 0, stream>>>(P, Q, l1w1, l1b1, l1w2, l1b2);
        conv4d<10, 1, false><<<HW, 256, 0, stream>>>(Q, S, l2w1, l2b1, l2w2, l2b2);

        // branch 2 (transposed orientation == swap w1/w2 roles)
        conv4d<1, 10, false><<<HW, 256, 0, stream>>>(C1, P, l0w2, l0b2, l0w1, l0b1);
        conv4d<10, 10, false><<<HW, 256, 0, stream>>>(P, Q, l1w2, l1b2, l1w1, l1b1);
        conv4d<10, 1, true><<<HW, 256, 0, stream>>>(Q, S, l2w2, l2b2, l2w1, l2b1);

        // second mutual matching + mask + softmax
        colmax_part<<<32, 256, 0, stream>>>(S, PART);
        colmax_comb<<<4, 256, 0, stream>>>(PART, MB1);
        mm_softmax<<<HW, 256, 0, stream>>>(S, MB1, mask_b, ATTN);

        // weighted_v = einsum('cs,qs->cq') for this batch
        dim3 ggrid(16, 4);
        gemm_vat<<<ggrid, 256, 0, stream>>>(v_b, ATTN, out_b);
    }
}

// Round 4
// 1659.925 us; speedup vs baseline: 2.8690x; 2.8690x over previous
//
#include <hip/hip_runtime.h>
#include <math.h>

#define BN 4
#define HW 1024
#define SP 1024

static constexpr float EPS = 1e-5f;
static constexpr float TEMPF = 3.0f;
static constexpr float MASK_FILL = 1e-4f;

// ---------------- reductions ----------------
__device__ __forceinline__ float wave_max(float v) {
    for (int o = 32; o; o >>= 1) v = fmaxf(v, __shfl_xor(v, o));
    return v;
}
__device__ __forceinline__ float wave_sum(float v) {
    for (int o = 32; o; o >>= 1) v += __shfl_xor(v, o);
    return v;
}
__device__ __forceinline__ float block_max(float v, float* red) {
    v = wave_max(v);
    int w = threadIdx.x >> 6;
    if ((threadIdx.x & 63) == 0) red[w] = v;
    __syncthreads();
    v = fmaxf(fmaxf(red[0], red[1]), fmaxf(red[2], red[3]));
    __syncthreads();
    return v;
}
__device__ __forceinline__ float block_sum(float v, float* red) {
    v = wave_sum(v);
    int w = threadIdx.x >> 6;
    if ((threadIdx.x & 63) == 0) red[w] = v;
    __syncthreads();
    v = red[0] + red[1] + red[2] + red[3];
    __syncthreads();
    return v;
}

// ---------------- column max over hw for each sp (per batch) ----------------
// grid: 256 blocks, 256 thr; each block reduces 4 hw-rows with float4 loads.
__global__ void colmax_part(const float* __restrict__ in, float* __restrict__ part) {
    int blk = blockIdx.x;
    const float* base = in + (size_t)blk * 4 * SP;
    int p4 = threadIdx.x << 2;
    float4 m = {-INFINITY, -INFINITY, -INFINITY, -INFINITY};
#pragma unroll
    for (int r = 0; r < 4; ++r) {
        float4 v = *(const float4*)&base[(size_t)r * SP + p4];
        m.x = fmaxf(m.x, v.x); m.y = fmaxf(m.y, v.y);
        m.z = fmaxf(m.z, v.z); m.w = fmaxf(m.w, v.w);
    }
    *(float4*)&part[(size_t)blk * SP + p4] = m;
}

// grid: 4 blocks, 256 thr: combine 256 partials, store 1/(max+EPS)
__global__ void colmax_comb(const float* __restrict__ part, float* __restrict__ binv) {
    int col = (blockIdx.x << 8) + threadIdx.x;
    float m = -INFINITY;
    for (int c = 0; c < 256; ++c) m = fmaxf(m, part[(size_t)c * SP + col]);
    binv[col] = 1.0f / (m + EPS);
}

// ---------------- mutual matching (row-max fused), per batch ----------------
__global__ void mm_rows(const float* __restrict__ in, const float* __restrict__ binv,
                        float* __restrict__ out) {
    __shared__ float red[4];
    int row = blockIdx.x;
    int p4 = threadIdx.x << 2;
    float4 v = *(const float4*)&in[(size_t)row * SP + p4];
    float m = fmaxf(fmaxf(v.x, v.y), fmaxf(v.z, v.w));
    m = block_max(m, red);
    float rinv = 1.0f / (m + EPS);
    float4 bi = *(const float4*)&binv[p4];
    float4 o;
    o.x = v.x * v.x * v.x * rinv * bi.x;
    o.y = v.y * v.y * v.y * rinv * bi.y;
    o.z = v.z * v.z * v.z * rinv * bi.z;
    o.w = v.w * v.w * v.w * rinv * bi.w;
    *(float4*)&out[(size_t)row * SP + p4] = o;
}

// ---------------- 4D conv layer (per batch) ----------------
// out[co,h,w,hs,ws] = relu( b1[co]+b2[co]
//    + sum_ci,tap in[ci,h+dh,w+dw,hs,ws]*whw[co,ci,tap]      (o1: neighbor planes, global)
//    + sum_ci,tap in[ci,h,w,hs+dh,ws+dw]*wsp[co,ci,tap] )    (o2: in-plane shifts, LDS)
// grid: HW blocks (one (h,w) each), 256 thr; thread owns 4 consecutive sp.
// One ci-plane staged at a time, double-buffered, 1 barrier/ci. Weights read
// via wave-uniform global loads (scalar cache).
template <int CI, int CO, bool ADD>
__global__ __launch_bounds__(256, 4) void conv4d(const float* __restrict__ in,
                                                 float* __restrict__ out,
                                                 const float* __restrict__ whw,
                                                 const float* __restrict__ bhw,
                                                 const float* __restrict__ wsp,
                                                 const float* __restrict__ bsp) {
    __shared__ float tile[2][SP];
    int hw = blockIdx.x;
    int h = hw >> 5, w = hw & 31;
    int tid = threadIdx.x;
    int p4 = tid << 2;   // 4 consecutive sp, same hs row (ws0 <= 28)
    int ws0 = p4 & 31;
    int hs = p4 >> 5;

    float acc[CO][4];
#pragma unroll
    for (int co = 0; co < CO; ++co) {
        float bsum = bhw[co] + bsp[co];
#pragma unroll
        for (int k = 0; k < 4; ++k) acc[co][k] = bsum;
    }

    float4 pre = *(const float4*)&in[(size_t)hw * SP + p4];  // ci=0 in-plane
    for (int ci = 0; ci < CI; ++ci) {
        float* tl = tile[ci & 1];
        *(float4*)&tl[p4] = pre;
        __syncthreads();
        if (ci + 1 < CI)
            pre = *(const float4*)&in[((size_t)(ci + 1) * HW + hw) * SP + p4];
        const float* inc = in + (size_t)ci * HW * SP;
#pragma unroll
        for (int dh = -1; dh <= 1; ++dh) {
            bool hok = (unsigned)(h + dh) < 32u;
            bool v2 = (unsigned)(hs + dh) < 32u;
            int b2 = p4 + dh * 32;
            float4 c4 = {0.f, 0.f, 0.f, 0.f};
            if (v2) c4 = *(const float4*)&tl[b2];
            float lm = (v2 && ws0 > 0) ? tl[b2 - 1] : 0.0f;
            float lp = (v2 && ws0 < 28) ? tl[b2 + 4] : 0.0f;
            float4 l4[3];
            l4[0] = {lm, c4.x, c4.y, c4.z};   // dw=-1
            l4[1] = c4;                        // dw=0
            l4[2] = {c4.y, c4.z, c4.w, lp};   // dw=+1
#pragma unroll
            for (int dwi = 0; dwi < 3; ++dwi) {
                int dw = dwi - 1;
                bool v1 = hok && ((unsigned)(w + dw) < 32u);
                float4 g4 = {0.f, 0.f, 0.f, 0.f};
                if (v1) g4 = *(const float4*)&inc[(size_t)(hw + dh * 32 + dw) * SP + p4];
                int tap = (dh + 1) * 3 + dwi;
#pragma unroll
                for (int co = 0; co < CO; ++co) {
                    float w1v = whw[(co * CI + ci) * 9 + tap];  // uniform -> s_load
                    float w2v = wsp[(co * CI + ci) * 9 + tap];
                    acc[co][0] = fmaf(g4.x, w1v, fmaf(l4[dwi].x, w2v, acc[co][0]));
                    acc[co][1] = fmaf(g4.y, w1v, fmaf(l4[dwi].y, w2v, acc[co][1]));
                    acc[co][2] = fmaf(g4.z, w1v, fmaf(l4[dwi].z, w2v, acc[co][2]));
                    acc[co][3] = fmaf(g4.w, w1v, fmaf(l4[dwi].w, w2v, acc[co][3]));
                }
            }
        }
        __syncthreads();
    }

#pragma unroll
    for (int co = 0; co < CO; ++co) {
        float* op = out + ((size_t)co * HW + hw) * SP + p4;
        float4 r;
        r.x = fmaxf(acc[co][0], 0.0f);
        r.y = fmaxf(acc[co][1], 0.0f);
        r.z = fmaxf(acc[co][2], 0.0f);
        r.w = fmaxf(acc[co][3], 0.0f);
        if (ADD) {
            float4 old = *(const float4*)op;
            r.x += old.x; r.y += old.y; r.z += old.z; r.w += old.w;
        }
        *(float4*)op = r;
    }
}

// ---------------- mutual matching + mask + softmax (per batch) ----------------
__global__ void mm_softmax(const float* __restrict__ s, const float* __restrict__ binv,
                           const int* __restrict__ mask, float* __restrict__ attn) {
    __shared__ float red[4];
    int row = blockIdx.x;
    int p4 = threadIdx.x << 2;
    float4 v = *(const float4*)&s[(size_t)row * SP + p4];
    float m = fmaxf(fmaxf(v.x, v.y), fmaxf(v.z, v.w));
    m = block_max(m, red);
    float rinv = 1.0f / (m + EPS);
    float4 bi = *(const float4*)&binv[p4];
    int4 mk = *(const int4*)&mask[p4];
    float lg[4];
    lg[0] = (mk.x != 0) ? MASK_FILL * TEMPF : v.x * v.x * v.x * rinv * bi.x * TEMPF;
    lg[1] = (mk.y != 0) ? MASK_FILL * TEMPF : v.y * v.y * v.y * rinv * bi.y * TEMPF;
    lg[2] = (mk.z != 0) ? MASK_FILL * TEMPF : v.z * v.z * v.z * rinv * bi.z * TEMPF;
    lg[3] = (mk.w != 0) ? MASK_FILL * TEMPF : v.w * v.w * v.w * rinv * bi.w * TEMPF;
    float lm = fmaxf(fmaxf(lg[0], lg[1]), fmaxf(lg[2], lg[3]));
    lm = block_max(lm, red);
    float e[4], ss = 0.0f;
#pragma unroll
    for (int k = 0; k < 4; ++k) {
        e[k] = expf(lg[k] - lm);
        ss += e[k];
    }
    ss = block_sum(ss, red);
    float inv = 1.0f / ss;
    float4 o = {e[0] * inv, e[1] * inv, e[2] * inv, e[3] * inv};
    *(float4*)&attn[(size_t)row * SP + p4] = o;
}

// ---------------- einsum GEMM: out[c,q] = sum_s V[c,s]*A[q,s] (per batch) ----------------
__global__ __launch_bounds__(256) void gemm_vat(const float* __restrict__ V,
                                                const float* __restrict__ A,
                                                float* __restrict__ out) {
    __shared__ float As[64][36];
    __shared__ float Bs[64][36];
    int c0 = blockIdx.y * 64, q0 = blockIdx.x * 64;
    int tr = threadIdx.x & 15, tc = threadIdx.x >> 4;
    float acc[4][4] = {};
    for (int k0 = 0; k0 < 1024; k0 += 32) {
#pragma unroll
        for (int j = 0; j < 2; ++j) {
            int idx = threadIdx.x + j * 256;
            int row = idx >> 3, c4 = (idx & 7) * 4;
            *(float4*)&As[row][c4] = *(const float4*)&V[(size_t)(c0 + row) * 1024 + k0 + c4];
            *(float4*)&Bs[row][c4] = *(const float4*)&A[(size_t)(q0 + row) * 1024 + k0 + c4];
        }
        __syncthreads();
#pragma unroll
        for (int kk = 0; kk < 8; ++kk) {
            float4 a[4], bb[4];
#pragma unroll
            for (int i = 0; i < 4; ++i) a[i] = *(float4*)&As[tr * 4 + i][kk * 4];
#pragma unroll
            for (int j = 0; j < 4; ++j) bb[j] = *(float4*)&Bs[tc * 4 + j][kk * 4];
#pragma unroll
            for (int i = 0; i < 4; ++i)
#pragma unroll
                for (int j = 0; j < 4; ++j)
                    acc[i][j] += a[i].x * bb[j].x + a[i].y * bb[j].y +
                                 a[i].z * bb[j].z + a[i].w * bb[j].w;
        }
        __syncthreads();
    }
#pragma unroll
    for (int i = 0; i < 4; ++i) {
        float4 o = {acc[i][0], acc[i][1], acc[i][2], acc[i][3]};
        *(float4*)&out[(size_t)(c0 + tr * 4 + i) * 1024 + q0 + tc * 4] = o;
    }
}

extern "C" void kernel_launch(void* const* d_in, const int* in_sizes, int n_in,
                              void* d_out, int out_size, void* d_ws, size_t ws_size,
                              hipStream_t stream) {
    const float* corr = (const float*)d_in[0];
    const float* v = (const float*)d_in[1];
    const int* mask = (const int*)d_in[2];
    const float* l0w1 = (const float*)d_in[3];
    const float* l0b1 = (const float*)d_in[4];
    const float* l0w2 = (const float*)d_in[5];
    const float* l0b2 = (const float*)d_in[6];
    const float* l1w1 = (const float*)d_in[7];
    const float* l1b1 = (const float*)d_in[8];
    const float* l1w2 = (const float*)d_in[9];
    const float* l1b2 = (const float*)d_in[10];
    const float* l2w1 = (const float*)d_in[11];
    const float* l2b1 = (const float*)d_in[12];
    const float* l2w2 = (const float*)d_in[13];
    const float* l2b2 = (const float*)d_in[14];

    // per-batch workspace: P,Q (10ch) + C1,S (1ch) + reductions  ~89.4 MB
    float* W = (float*)d_ws;
    const size_t CH10 = (size_t)10 * HW * SP;
    const size_t CH1 = (size_t)HW * SP;
    float* P = W;
    float* Q = P + CH10;
    float* C1 = Q + CH10;
    float* S = C1 + CH1;
    float* PART = S + CH1;           // 256*SP
    float* MB0 = PART + 256 * SP;
    float* MB1 = MB0 + SP;
    float* ATTN = C1;  // C1 dead after branch-2 layer 0 of this batch
    float* out = (float*)d_out;
    (void)in_sizes; (void)n_in; (void)out_size; (void)ws_size;

    for (int b = 0; b < BN; ++b) {
        const float* corr_b = corr + (size_t)b * HW * SP;
        const float* v_b = v + (size_t)b * 256 * SP;
        const int* mask_b = mask + (size_t)b * SP;
        float* out_b = out + (size_t)b * 256 * SP;

        // first mutual matching
        colmax_part<<<256, 256, 0, stream>>>(corr_b, PART);
        colmax_comb<<<4, 256, 0, stream>>>(PART, MB0);
        mm_rows<<<HW, 256, 0, stream>>>(corr_b, MB0, C1);

        // branch 1: (h,w)-conv uses w1, (hs,ws)-conv uses w2
        conv4d<1, 10, false><<<HW, 256, 0, stream>>>(C1, P, l0w1, l0b1, l0w2, l0b2);
        conv4d<10, 10, false><<<HW, 256, 0, stream>>>(P, Q, l1w1, l1b1, l1w2, l1b2);
        conv4d<10, 1, false><<<HW, 256, 0, stream>>>(Q, S, l2w1, l2b1, l2w2, l2b2);

        // branch 2 (transposed orientation == swap w1/w2 roles)
        conv4d<1, 10, false><<<HW, 256, 0, stream>>>(C1, P, l0w2, l0b2, l0w1, l0b1);
        conv4d<10, 10, false><<<HW, 256, 0, stream>>>(P, Q, l1w2, l1b2, l1w1, l1b1);
        conv4d<10, 1, true><<<HW, 256, 0, stream>>>(Q, S, l2w2, l2b2, l2w1, l2b1);

        // second mutual matching + mask + softmax
        colmax_part<<<256, 256, 0, stream>>>(S, PART);
        colmax_comb<<<4, 256, 0, stream>>>(PART, MB1);
        mm_softmax<<<HW, 256, 0, stream>>>(S, MB1, mask_b, ATTN);

        // weighted_v = einsum('cs,qs->cq') for this batch
        dim3 ggrid(16, 4);
        gemm_vat<<<ggrid, 256, 0, stream>>>(v_b, ATTN, out_b);
    }
}

// Round 5
// 1587.522 us; speedup vs baseline: 2.9998x; 1.0456x over previous
//
#include <hip/hip_runtime.h>
#include <math.h>

#define BN 4
#define HW 1024
#define SP 1024

static constexpr float EPS = 1e-5f;
static constexpr float TEMPF = 3.0f;
static constexpr float MASK_FILL = 1e-4f;

// ---------------- reductions ----------------
__device__ __forceinline__ float wave_max(float v) {
    for (int o = 32; o; o >>= 1) v = fmaxf(v, __shfl_xor(v, o));
    return v;
}
__device__ __forceinline__ float wave_sum(float v) {
    for (int o = 32; o; o >>= 1) v += __shfl_xor(v, o);
    return v;
}
__device__ __forceinline__ float block_max(float v, float* red) {
    v = wave_max(v);
    int w = threadIdx.x >> 6;
    if ((threadIdx.x & 63) == 0) red[w] = v;
    __syncthreads();
    v = fmaxf(fmaxf(red[0], red[1]), fmaxf(red[2], red[3]));
    __syncthreads();
    return v;
}
__device__ __forceinline__ float block_sum(float v, float* red) {
    v = wave_sum(v);
    int w = threadIdx.x >> 6;
    if ((threadIdx.x & 63) == 0) red[w] = v;
    __syncthreads();
    v = red[0] + red[1] + red[2] + red[3];
    __syncthreads();
    return v;
}

// ---------------- column max over hw for each sp (per batch) ----------------
// grid: 256 blocks, 256 thr; each block reduces 4 hw-rows. SUM2: in = s1+s2.
template <bool SUM2>
__global__ void colmax_part(const float* __restrict__ in1, const float* __restrict__ in2,
                            float* __restrict__ part) {
    int blk = blockIdx.x;
    int p4 = threadIdx.x << 2;
    size_t base = (size_t)blk * 4 * SP + p4;
    float4 m = {-INFINITY, -INFINITY, -INFINITY, -INFINITY};
#pragma unroll
    for (int r = 0; r < 4; ++r) {
        float4 v = *(const float4*)&in1[base + (size_t)r * SP];
        if (SUM2) {
            float4 u = *(const float4*)&in2[base + (size_t)r * SP];
            v.x += u.x; v.y += u.y; v.z += u.z; v.w += u.w;
        }
        m.x = fmaxf(m.x, v.x); m.y = fmaxf(m.y, v.y);
        m.z = fmaxf(m.z, v.z); m.w = fmaxf(m.w, v.w);
    }
    *(float4*)&part[(size_t)blk * SP + p4] = m;
}

// grid: 4 blocks, 256 thr: combine 256 partials, store 1/(max+EPS)
__global__ void colmax_comb(const float* __restrict__ part, float* __restrict__ binv) {
    int col = (blockIdx.x << 8) + threadIdx.x;
    float m = -INFINITY;
    for (int c = 0; c < 256; ++c) m = fmaxf(m, part[(size_t)c * SP + col]);
    binv[col] = 1.0f / (m + EPS);
}

// ---------------- mutual matching (row-max fused), per batch ----------------
__global__ void mm_rows(const float* __restrict__ in, const float* __restrict__ binv,
                        float* __restrict__ out) {
    __shared__ float red[4];
    int row = blockIdx.x;
    int p4 = threadIdx.x << 2;
    float4 v = *(const float4*)&in[(size_t)row * SP + p4];
    float m = fmaxf(fmaxf(v.x, v.y), fmaxf(v.z, v.w));
    m = block_max(m, red);
    float rinv = 1.0f / (m + EPS);
    float4 bi = *(const float4*)&binv[p4];
    float4 o;
    o.x = v.x * v.x * v.x * rinv * bi.x;
    o.y = v.y * v.y * v.y * rinv * bi.y;
    o.z = v.z * v.z * v.z * rinv * bi.z;
    o.w = v.w * v.w * v.w * rinv * bi.w;
    *(float4*)&out[(size_t)row * SP + p4] = o;
}

// ---------------- 4D conv layer (per batch), branch-parallel ----------------
// branch = blockIdx.y + branch_base. branch 0: in0->out0, whw=wA, wsp=wB.
// branch 1: in1->out1, whw=wB, wsp=wA (transposed-orientation stack).
// out[co,hw,sp] = relu( bA[co]+bB[co]
//    + sum_ci,tap in[ci,hw+taphw,sp]*whw[..]   (neighbor planes, global/L2)
//    + sum_ci,tap in[ci,hw,sp+tapsp]*wsp[..] ) (in-plane shifts, LDS staged)
template <int CI, int CO>
__global__ __launch_bounds__(256, 4) void conv4d(
    const float* __restrict__ in0, const float* __restrict__ in1,
    float* __restrict__ out0, float* __restrict__ out1,
    const float* __restrict__ wA, const float* __restrict__ bA,
    const float* __restrict__ wB, const float* __restrict__ bB,
    int branch_base) {
    __shared__ float tile[2][SP];
    int branch = blockIdx.y + branch_base;
    const float* in = branch ? in1 : in0;
    float* out = branch ? out1 : out0;
    const float* whw = branch ? wB : wA;
    const float* wsp = branch ? wA : wB;

    int hw = blockIdx.x;
    int h = hw >> 5, w = hw & 31;
    int tid = threadIdx.x;
    int p4 = tid << 2;   // 4 consecutive sp, same hs row (ws0 <= 28)
    int ws0 = p4 & 31;
    int hs = p4 >> 5;

    float acc[CO][4];
#pragma unroll
    for (int co = 0; co < CO; ++co) {
        float bsum = bA[co] + bB[co];
#pragma unroll
        for (int k = 0; k < 4; ++k) acc[co][k] = bsum;
    }

    float4 pre = *(const float4*)&in[(size_t)hw * SP + p4];  // ci=0 in-plane
    for (int ci = 0; ci < CI; ++ci) {
        float* tl = tile[ci & 1];
        *(float4*)&tl[p4] = pre;
        __syncthreads();
        if (ci + 1 < CI)
            pre = *(const float4*)&in[((size_t)(ci + 1) * HW + hw) * SP + p4];
        const float* inc = in + (size_t)ci * HW * SP;
#pragma unroll
        for (int dh = -1; dh <= 1; ++dh) {
            bool hok = (unsigned)(h + dh) < 32u;
            bool v2 = (unsigned)(hs + dh) < 32u;
            int b2 = p4 + dh * 32;
            float4 c4 = {0.f, 0.f, 0.f, 0.f};
            if (v2) c4 = *(const float4*)&tl[b2];
            float lm = (v2 && ws0 > 0) ? tl[b2 - 1] : 0.0f;
            float lp = (v2 && ws0 < 28) ? tl[b2 + 4] : 0.0f;
            float4 l4[3];
            l4[0] = {lm, c4.x, c4.y, c4.z};   // dw=-1
            l4[1] = c4;                        // dw=0
            l4[2] = {c4.y, c4.z, c4.w, lp};   // dw=+1
#pragma unroll
            for (int dwi = 0; dwi < 3; ++dwi) {
                int dw = dwi - 1;
                bool v1 = hok && ((unsigned)(w + dw) < 32u);
                float4 g4 = {0.f, 0.f, 0.f, 0.f};
                if (v1) g4 = *(const float4*)&inc[(size_t)(hw + dh * 32 + dw) * SP + p4];
                int tap = (dh + 1) * 3 + dwi;
#pragma unroll
                for (int co = 0; co < CO; ++co) {
                    float w1v = whw[(co * CI + ci) * 9 + tap];  // uniform -> s_load
                    float w2v = wsp[(co * CI + ci) * 9 + tap];
                    acc[co][0] = fmaf(g4.x, w1v, fmaf(l4[dwi].x, w2v, acc[co][0]));
                    acc[co][1] = fmaf(g4.y, w1v, fmaf(l4[dwi].y, w2v, acc[co][1]));
                    acc[co][2] = fmaf(g4.z, w1v, fmaf(l4[dwi].z, w2v, acc[co][2]));
                    acc[co][3] = fmaf(g4.w, w1v, fmaf(l4[dwi].w, w2v, acc[co][3]));
                }
            }
        }
        __syncthreads();
    }

#pragma unroll
    for (int co = 0; co < CO; ++co) {
        float* op = out + ((size_t)co * HW + hw) * SP + p4;
        float4 r;
        r.x = fmaxf(acc[co][0], 0.0f);
        r.y = fmaxf(acc[co][1], 0.0f);
        r.z = fmaxf(acc[co][2], 0.0f);
        r.w = fmaxf(acc[co][3], 0.0f);
        *(float4*)op = r;
    }
}

// ---------------- mutual matching + mask + softmax (per batch), s = s1+s2 ----------------
__global__ void mm_softmax(const float* __restrict__ s1, const float* __restrict__ s2,
                           const float* __restrict__ binv, const int* __restrict__ mask,
                           float* __restrict__ attn) {
    __shared__ float red[4];
    int row = blockIdx.x;
    int p4 = threadIdx.x << 2;
    float4 v = *(const float4*)&s1[(size_t)row * SP + p4];
    float4 u = *(const float4*)&s2[(size_t)row * SP + p4];
    v.x += u.x; v.y += u.y; v.z += u.z; v.w += u.w;
    float m = fmaxf(fmaxf(v.x, v.y), fmaxf(v.z, v.w));
    m = block_max(m, red);
    float rinv = 1.0f / (m + EPS);
    float4 bi = *(const float4*)&binv[p4];
    int4 mk = *(const int4*)&mask[p4];
    float lg[4];
    lg[0] = (mk.x != 0) ? MASK_FILL * TEMPF : v.x * v.x * v.x * rinv * bi.x * TEMPF;
    lg[1] = (mk.y != 0) ? MASK_FILL * TEMPF : v.y * v.y * v.y * rinv * bi.y * TEMPF;
    lg[2] = (mk.z != 0) ? MASK_FILL * TEMPF : v.z * v.z * v.z * rinv * bi.z * TEMPF;
    lg[3] = (mk.w != 0) ? MASK_FILL * TEMPF : v.w * v.w * v.w * rinv * bi.w * TEMPF;
    float lm = fmaxf(fmaxf(lg[0], lg[1]), fmaxf(lg[2], lg[3]));
    lm = block_max(lm, red);
    float e[4], ss = 0.0f;
#pragma unroll
    for (int k = 0; k < 4; ++k) {
        e[k] = expf(lg[k] - lm);
        ss += e[k];
    }
    ss = block_sum(ss, red);
    float inv = 1.0f / ss;
    float4 o = {e[0] * inv, e[1] * inv, e[2] * inv, e[3] * inv};
    *(float4*)&attn[(size_t)row * SP + p4] = o;
}

// ---------------- einsum GEMM: out[c,q] = sum_s V[c,s]*A[q,s] (per batch) ----------------
__global__ __launch_bounds__(256) void gemm_vat(const float* __restrict__ V,
                                                const float* __restrict__ A,
                                                float* __restrict__ out) {
    __shared__ float As[64][36];
    __shared__ float Bs[64][36];
    int c0 = blockIdx.y * 64, q0 = blockIdx.x * 64;
    int tr = threadIdx.x & 15, tc = threadIdx.x >> 4;
    float acc[4][4] = {};
    for (int k0 = 0; k0 < 1024; k0 += 32) {
#pragma unroll
        for (int j = 0; j < 2; ++j) {
            int idx = threadIdx.x + j * 256;
            int row = idx >> 3, c4 = (idx & 7) * 4;
            *(float4*)&As[row][c4] = *(const float4*)&V[(size_t)(c0 + row) * 1024 + k0 + c4];
            *(float4*)&Bs[row][c4] = *(const float4*)&A[(size_t)(q0 + row) * 1024 + k0 + c4];
        }
        __syncthreads();
#pragma unroll
        for (int kk = 0; kk < 8; ++kk) {
            float4 a[4], bb[4];
#pragma unroll
            for (int i = 0; i < 4; ++i) a[i] = *(float4*)&As[tr * 4 + i][kk * 4];
#pragma unroll
            for (int j = 0; j < 4; ++j) bb[j] = *(float4*)&Bs[tc * 4 + j][kk * 4];
#pragma unroll
            for (int i = 0; i < 4; ++i)
#pragma unroll
                for (int j = 0; j < 4; ++j)
                    acc[i][j] += a[i].x * bb[j].x + a[i].y * bb[j].y +
                                 a[i].z * bb[j].z + a[i].w * bb[j].w;
        }
        __syncthreads();
    }
#pragma unroll
    for (int i = 0; i < 4; ++i) {
        float4 o = {acc[i][0], acc[i][1], acc[i][2], acc[i][3]};
        *(float4*)&out[(size_t)(c0 + tr * 4 + i) * 1024 + q0 + tc * 4] = o;
    }
}

extern "C" void kernel_launch(void* const* d_in, const int* in_sizes, int n_in,
                              void* d_out, int out_size, void* d_ws, size_t ws_size,
                              hipStream_t stream) {
    const float* corr = (const float*)d_in[0];
    const float* v = (const float*)d_in[1];
    const int* mask = (const int*)d_in[2];
    const float* l0w1 = (const float*)d_in[3];
    const float* l0b1 = (const float*)d_in[4];
    const float* l0w2 = (const float*)d_in[5];
    const float* l0b2 = (const float*)d_in[6];
    const float* l1w1 = (const float*)d_in[7];
    const float* l1b1 = (const float*)d_in[8];
    const float* l1w2 = (const float*)d_in[9];
    const float* l1b2 = (const float*)d_in[10];
    const float* l2w1 = (const float*)d_in[11];
    const float* l2b1 = (const float*)d_in[12];
    const float* l2w2 = (const float*)d_in[13];
    const float* l2b2 = (const float*)d_in[14];

    float* W = (float*)d_ws;
    const size_t CH10 = (size_t)10 * HW * SP;
    const size_t CH1 = (size_t)HW * SP;
    const size_t need_par = (4 * CH10 + 2 * CH1) * sizeof(float);  // ~176 MB
    bool par = ws_size >= need_par;

    float *P1, *Q1, *P2, *Q2, *C1, *S1, *S2;
    if (par) {
        P1 = W; Q1 = P1 + CH10; P2 = Q1 + CH10; Q2 = P2 + CH10;
        S1 = Q2 + CH10; S2 = S1 + CH1;
        C1 = Q1;  // C1 read only in L0; Q1 written from L1 on
    } else {
        P1 = W; Q1 = P1 + CH10; C1 = Q1 + CH10; S1 = C1 + CH1; S2 = S1 + CH1;
        P2 = P1; Q2 = Q1;  // sequential two-pass
    }
    // scratch region inside P1: dead during convs' use of these words
    float* PART = P1;                 // used before L0 / after L2 only
    float* MB0 = P1 + 256 * SP;
    float* MB1 = MB0 + SP;
    float* ATTN = P1 + 512 * SP;      // written after L1 (P1 dead)
    float* out = (float*)d_out;
    (void)in_sizes; (void)n_in; (void)out_size;

    for (int b = 0; b < BN; ++b) {
        const float* corr_b = corr + (size_t)b * HW * SP;
        const float* v_b = v + (size_t)b * 256 * SP;
        const int* mask_b = mask + (size_t)b * SP;
        float* out_b = out + (size_t)b * 256 * SP;

        // first mutual matching
        colmax_part<false><<<256, 256, 0, stream>>>(corr_b, corr_b, PART);
        colmax_comb<<<4, 256, 0, stream>>>(PART, MB0);
        mm_rows<<<HW, 256, 0, stream>>>(corr_b, MB0, C1);

        if (par) {
            dim3 g(HW, 2);  // both branches concurrent
            conv4d<1, 10><<<g, 256, 0, stream>>>(C1, C1, P1, P2, l0w1, l0b1, l0w2, l0b2, 0);
            conv4d<10, 10><<<g, 256, 0, stream>>>(P1, P2, Q1, Q2, l1w1, l1b1, l1w2, l1b2, 0);
            conv4d<10, 1><<<g, 256, 0, stream>>>(Q1, Q2, S1, S2, l2w1, l2b1, l2w2, l2b2, 0);
        } else {
            conv4d<1, 10><<<HW, 256, 0, stream>>>(C1, C1, P1, P1, l0w1, l0b1, l0w2, l0b2, 0);
            conv4d<10, 10><<<HW, 256, 0, stream>>>(P1, P1, Q1, Q1, l1w1, l1b1, l1w2, l1b2, 0);
            conv4d<10, 1><<<HW, 256, 0, stream>>>(Q1, Q1, S1, S1, l2w1, l2b1, l2w2, l2b2, 0);
            conv4d<1, 10><<<HW, 256, 0, stream>>>(C1, C1, P1, P1, l0w1, l0b1, l0w2, l0b2, 1);
            conv4d<10, 10><<<HW, 256, 0, stream>>>(P1, P1, Q1, Q1, l1w1, l1b1, l1w2, l1b2, 1);
            conv4d<10, 1><<<HW, 256, 0, stream>>>(Q1, Q1, S2, S2, l2w1, l2b1, l2w2, l2b2, 1);
        }

        // second mutual matching + mask + softmax on S1+S2
        colmax_part<true><<<256, 256, 0, stream>>>(S1, S2, PART);
        colmax_comb<<<4, 256, 0, stream>>>(PART, MB1);
        mm_softmax<<<HW, 256, 0, stream>>>(S1, S2, MB1, mask_b, ATTN);

        // weighted_v = einsum('cs,qs->cq') for this batch
        dim3 ggrid(16, 4);
        gemm_vat<<<ggrid, 256, 0, stream>>>(v_b, ATTN, out_b);
    }
}